// Round 2
// baseline (7378.235 us; speedup 1.0000x reference)
//
#include <hip/hip_runtime.h>
#include <hip/hip_bf16.h>
#include <math.h>

// Problem constants (GRUAttnDecoder): B=16, ENC=512, T=64, DIM=768, VOCAB=21128
#define Bdim 16
#define ENC 512
#define Tn 64
#define DIM 768
#define VOCAB 21128
#define SCALEF 0.03608439182435161f  // 1/sqrt(768)
#define NEGF   -1e30f
#define NBLK 256
#define RU_PER 6   // r|u rows per block (1536/256)
#define C_PER 3    // c rows per block  (768/256)
#define DYN_LDS (96 * 1024)  // forces 1 block/CU -> exactly 32 blocks per XCD

__device__ __forceinline__ float wred_sum(float v) {
#pragma unroll
  for (int m = 32; m >= 1; m >>= 1) v += __shfl_xor(v, m, 64);
  return v;
}
__device__ __forceinline__ float sigmf(float x) { return 1.0f / (1.0f + __expf(-x)); }

// coherent (IF-level, L2-bypassing) access helpers
__device__ __forceinline__ void astore(float* p, float v) {
  __hip_atomic_store(p, v, __ATOMIC_RELAXED, __HIP_MEMORY_SCOPE_AGENT);
}

// XCD-local (L2-level) atomic RMW: workgroup scope => no sc1 bit => the RMW
// executes in the issuing XCD's L2. Only valid when ALL touchers of the line
// are blocks on the SAME physical XCD (guaranteed via XCC_ID indexing with a
// 128B line per XCD).
__device__ __forceinline__ unsigned l2_fadd(unsigned* p, unsigned v) {
  return __hip_atomic_fetch_add(p, v, __ATOMIC_RELAXED, __HIP_MEMORY_SCOPE_WORKGROUP);
}
// XCD-local poll: sc0 load bypasses the CU L1 and is served by the XCD's L2
// (where l2_fadd's update lives). volatile asm => re-executed each call.
// NOTE "=&v" early-clobber: without it the 32-bit result may be allocated on
// top of the 64-bit address pair, corrupting the address after the first poll
// (the bug that hung the previous round).
__device__ __forceinline__ unsigned l2_poll(const unsigned* p) {
  unsigned v;
  asm volatile("global_load_dword %0, %1, off sc0\n\ts_waitcnt vmcnt(0)"
               : "=&v"(v) : "v"(p) : "memory");
  return v;
}

// Two-level grid barrier, low-contention edition.
// Arrival: L2-local leaf[xcd] fetch_add (cumulative across launches; the
// arrival whose count hits 0 mod 32 is the XCD leader for this barrier).
// Leader bumps the IF-level root (zeroed each launch), polls it until
// 8*(n+1) (only 8 pollers chip-wide on that line), then releases its XCD via
// the L2-local go[xcd] counter. Followers spin on go[xcd] in their own L2
// (sc0 loads), comparing against the launch-start baseline g0 with wrap-safe
// unsigned arithmetic. Fallback: every 64 spins a follower also checks the
// root release condition (agent load) — turns any sc0-semantics surprise
// into a slowdown instead of a deadlock.
// Data visibility: writers drain vmcnt(0) (agent stores ack from IF) before
// arrival, so root>=8*(n+1) implies all XCDs' data is at IF.
__device__ __forceinline__ void gbar(unsigned* leaf, unsigned* go, unsigned* root,
                                     unsigned g0, int n, int xcd) {
  __syncthreads();
  if (threadIdx.x == 0) {
    asm volatile("s_waitcnt vmcnt(0)" ::: "memory");
    const unsigned tgt = 8u * (unsigned)(n + 1);
    unsigned prev = l2_fadd(&leaf[xcd * 32], 1u);
    if (((prev + 1u) & 31u) == 0u) {
      // XCD leader for this barrier
      __hip_atomic_fetch_add(root, 1u, __ATOMIC_RELAXED, __HIP_MEMORY_SCOPE_AGENT);
      while (__hip_atomic_load(root, __ATOMIC_RELAXED, __HIP_MEMORY_SCOPE_AGENT) < tgt)
        __builtin_amdgcn_s_sleep(1);
      l2_fadd(&go[xcd * 32], 1u);
    } else {
      // follower: spin on the XCD-local go counter in this XCD's L2
      unsigned spins = 0;
      for (;;) {
        if ((unsigned)(l2_poll(&go[xcd * 32]) - g0) >= (unsigned)(n + 1)) break;
        if ((++spins & 63u) == 0u &&
            __hip_atomic_load(root, __ATOMIC_RELAXED, __HIP_MEMORY_SCOPE_AGENT) >= tgt)
          break;
        __builtin_amdgcn_s_sleep(1);
      }
    }
  }
  __syncthreads();
}

// bf16 pack helpers (manual RNE)
__device__ __forceinline__ unsigned int f2bf(float f) {
  unsigned int u = __float_as_uint(f);
  u += 0x7fffu + ((u >> 16) & 1u);
  return u >> 16;
}
__device__ __forceinline__ float bflo(unsigned int p) { return __uint_as_float(p << 16); }
__device__ __forceinline__ float bfhi(unsigned int p) { return __uint_as_float(p & 0xffff0000u); }

// ---------------- init ----------------
__global__ void k_zero_coh(unsigned long long* __restrict__ p, int n64) {
  int i = blockIdx.x * blockDim.x + threadIdx.x;
  int st = gridDim.x * blockDim.x;
  for (; i < n64; i += st)
    __hip_atomic_store(&p[i], 0ULL, __ATOMIC_RELAXED, __HIP_MEMORY_SCOPE_AGENT);
}

__global__ void k_h0(const float* __restrict__ init_h, float* __restrict__ h_all) {
  int i = blockIdx.x * blockDim.x + threadIdx.x;
  if (i < Bdim * DIM) h_all[i] = init_h[i % DIM];
}

// ---- precompute emb-part of gate preactivations + bias for all (t,b) ----
__global__ void __launch_bounds__(256, 2) k_pre(
    const int* __restrict__ din, const float* __restrict__ emb,
    const float* __restrict__ Wr, const float* __restrict__ br,
    const float* __restrict__ Wu, const float* __restrict__ bu,
    const float* __restrict__ Wc, const float* __restrict__ bc,
    float* __restrict__ P_ru, float* __restrict__ P_c) {
  const int nb = blockIdx.x, tbc = blockIdx.y;
  const int n = nb * 256 + threadIdx.x;
  const float* wrow;
  float bias;
  if (n < 768)       { wrow = Wr + n * 2304 + 768;          bias = br[n]; }
  else if (n < 1536) { wrow = Wu + (n - 768) * 2304 + 768;  bias = bu[n - 768]; }
  else               { wrow = Wc + (n - 1536) * 2304 + 768; bias = bc[n - 1536]; }
  int id[16];
#pragma unroll
  for (int i = 0; i < 16; ++i) {
    int row = tbc * 16 + i;  // row = t*16 + b
    id[i] = din[(row & 15) * Tn + (row >> 4)];
  }
  float acc[16];
#pragma unroll
  for (int i = 0; i < 16; ++i) acc[i] = bias;
  for (int k = 0; k < DIM; k += 4) {
    float4 w = *(const float4*)(wrow + k);
#pragma unroll
    for (int i = 0; i < 16; ++i) {
      float4 x = *(const float4*)(emb + (size_t)id[i] * DIM + k);
      acc[i] = fmaf(w.x, x.x, fmaf(w.y, x.y, fmaf(w.z, x.z, fmaf(w.w, x.w, acc[i]))));
    }
  }
#pragma unroll
  for (int i = 0; i < 16; ++i) {
    int row = tbc * 16 + i;
    if (n < 1536) P_ru[(size_t)row * 1536 + n] = acc[i];
    else          P_c[(size_t)row * 768 + (n - 1536)] = acc[i];
  }
}

// ---- persistent sequential kernel: weights live in VGPRs for all 64 steps ----
// block identity: physical (xcd, slot<32).  attention: batch 2*xcd+(slot&1),
// chunk slot>>1 (32 enc positions) -> ctx L2-pinned per XCD by construction.
// gates: gid = xcd*32+slot owns ru rows gid*6.. and c rows gid*3.. ;
// wave w handles batches {2w, 2w+1}.
__global__ void __launch_bounds__(512, 2) k_seq(
    const float* __restrict__ ctx, const float* __restrict__ mask,
    const float* __restrict__ Wr, const float* __restrict__ Wu,
    const float* __restrict__ Wc,
    const float* __restrict__ P_ru, const float* __restrict__ P_c,
    float* __restrict__ h_all, float* __restrict__ attnacc,
    float* __restrict__ den, float* __restrict__ r_t, float* __restrict__ u_t,
    unsigned* __restrict__ slotctr, unsigned* __restrict__ leaf,
    unsigned* __restrict__ go, unsigned* __restrict__ root) {
  extern __shared__ float dynpad[];   // 96KB requested; only e_lds used
  float* e_lds = dynpad;              // [32]
  __shared__ int slot_sh;
  __shared__ unsigned g0_sh;
  const int tid = threadIdx.x;
  const int lane = tid & 63;
  const int wv = tid >> 6;  // 0..7
  int xcd;
  asm volatile("s_getreg_b32 %0, hwreg(HW_REG_XCC_ID)" : "=s"(xcd));
  xcd &= 7;
  if (tid == 0) {
    // slot assignment + per-launch go baseline; both L2-local, monotonic
    // across launches (slot = prev&31 since each launch adds exactly 32).
    unsigned ps = l2_fadd(&slotctr[xcd * 32], 1u);
    slot_sh = (int)(ps & 31u);
    g0_sh = l2_poll(&go[xcd * 32]);  // stable: no bump until all 32 arrive
  }
  __syncthreads();
  const int slot = slot_sh;            // 0..31 (1 block/CU guaranteed by LDS)
  const unsigned g0 = g0_sh;
  const int gid = xcd * 32 + slot;     // 0..255 unique
  const int bA = 2 * xcd + (slot & 1); // attention batch
  const int chunk = slot >> 1;         // 0..15 (32 positions)
  const int ru0 = gid * RU_PER;        // 0..1535
  const int c0g = gid * C_PER;         // 0..767
  const int b0 = 2 * wv;               // this wave's two batches

  // ---- stage this block's 9 W rows into per-lane VGPRs (packed bf16) ----
  // lane cols (x-layout [a(768)|h(768)]): chunk j<6: xcol = 4*lane + 256*j
  // source col: j<3 -> xcol (attn part); j>=3 -> 1536 + (xcol-768) (h part)
  unsigned int wreg[RU_PER + C_PER][12];
#pragma unroll
  for (int i = 0; i < RU_PER + C_PER; ++i) {
    int row;
    const float* src;
    if (i < RU_PER) {
      row = ru0 + i;
      src = (row < 768) ? (Wr + (size_t)row * 2304) : (Wu + (size_t)(row - 768) * 2304);
    } else {
      src = Wc + (size_t)(c0g + (i - RU_PER)) * 2304;
    }
#pragma unroll
    for (int j = 0; j < 6; ++j) {
      int xcol = 4 * lane + 256 * j;
      int scol = (j < 3) ? xcol : (1536 + xcol - 768);
      float4 v = *(const float4*)(src + scol);
      wreg[i][2 * j]     = (f2bf(v.x)) | (f2bf(v.y) << 16);
      wreg[i][2 * j + 1] = (f2bf(v.z)) | (f2bf(v.w) << 16);
    }
  }
  // attention mask-add for this wave's 4 positions
  float madd[4];
#pragma unroll
  for (int i = 0; i < 4; ++i)
    madd[i] = (1.0f - mask[bA * ENC + chunk * 32 + 4 * wv + i]) * NEGF;

  int bidx = 0;
  for (int t = 0; t < Tn; ++t) {
    // ================= phase A: attention for batch bA =================
    {
      const float* hrow = h_all + (size_t)(t * Bdim + bA) * DIM;
      float hreg[12];
#pragma unroll
      for (int j = 0; j < 12; ++j) hreg[j] = hrow[lane + 64 * j];
      float esum = 0.f;
#pragma unroll
      for (int i = 0; i < 4; ++i) {
        const int s = chunk * 32 + 4 * wv + i;
        const float* crow = ctx + ((size_t)(bA * ENC + s)) * DIM;
        float dot = 0.f;
#pragma unroll
        for (int j = 0; j < 12; ++j) dot = fmaf(crow[lane + 64 * j], hreg[j], dot);
        dot = wred_sum(dot);
        if (lane == 0) {
          float e = __expf(fmaf(dot, SCALEF, madd[i]));  // scores O(1): no max-sub
          e_lds[4 * wv + i] = e;
          esum += e;
        }
      }
      if (lane == 0) atomicAdd(&den[t * 32 + bA], esum);
      __syncthreads();
      // weighted partial sum over this chunk's 32 ctx rows
      const float* cb = ctx + ((size_t)(bA * ENC + chunk * 32)) * DIM;
      for (int c = tid; c < DIM; c += 512) {
        float acc = 0.f;
#pragma unroll 8
        for (int r = 0; r < 32; ++r) acc = fmaf(e_lds[r], cb[(size_t)r * DIM + c], acc);
        atomicAdd(&attnacc[(size_t)(t * Bdim + bA) * DIM + c], acc);
      }
    }
    gbar(leaf, go, root, g0, bidx++, xcd);

    // ================= phase B: r,u gates (reg-resident W) =================
    float4 xv[2][6];
#pragma unroll
    for (int bb = 0; bb < 2; ++bb) {
      const int b = b0 + bb;
      const float invd = 1.0f / den[t * 32 + b];  // fresh line, post-barrier
      const float* ab = attnacc + (size_t)(t * Bdim + b) * DIM;
      const float* hb = h_all + (size_t)(t * Bdim + b) * DIM;
#pragma unroll
      for (int j = 0; j < 3; ++j) {
        float4 a4 = *(const float4*)(ab + 4 * lane + 256 * j);
        xv[bb][j] = make_float4(a4.x * invd, a4.y * invd, a4.z * invd, a4.w * invd);
      }
#pragma unroll
      for (int j = 0; j < 3; ++j)
        xv[bb][3 + j] = *(const float4*)(hb + 4 * lane + 256 * j);
    }
#pragma unroll
    for (int i = 0; i < RU_PER; ++i) {
      float d0 = 0.f, d1 = 0.f;
#pragma unroll
      for (int j = 0; j < 6; ++j) {
        const unsigned int p0 = wreg[i][2 * j], p1 = wreg[i][2 * j + 1];
        const float w0 = bflo(p0), w1 = bfhi(p0), w2 = bflo(p1), w3 = bfhi(p1);
        d0 = fmaf(w0, xv[0][j].x, fmaf(w1, xv[0][j].y, fmaf(w2, xv[0][j].z, fmaf(w3, xv[0][j].w, d0))));
        d1 = fmaf(w0, xv[1][j].x, fmaf(w1, xv[1][j].y, fmaf(w2, xv[1][j].z, fmaf(w3, xv[1][j].w, d1))));
      }
      d0 = wred_sum(d0);
      d1 = wred_sum(d1);
      if (lane < 2) {
        const int b = b0 + lane;
        const float dd = lane ? d1 : d0;
        const int row = ru0 + i;
        const float s = sigmf(P_ru[(size_t)(t * Bdim + b) * 1536 + row] + dd);
        if (row < 768) astore(&r_t[(size_t)(t * Bdim + b) * DIM + row], s);
        else           astore(&u_t[(size_t)(t * Bdim + b) * DIM + (row - 768)], s);
      }
    }
    gbar(leaf, go, root, g0, bidx++, xcd);

    // ================= phase C: c gate + h update =================
#pragma unroll
    for (int bb = 0; bb < 2; ++bb) {
      const int b = b0 + bb;
      const float* rb = r_t + (size_t)(t * Bdim + b) * DIM;
#pragma unroll
      for (int j = 0; j < 3; ++j) {
        float4 rv = *(const float4*)(rb + 4 * lane + 256 * j);  // fresh line
        xv[bb][3 + j].x *= rv.x; xv[bb][3 + j].y *= rv.y;
        xv[bb][3 + j].z *= rv.z; xv[bb][3 + j].w *= rv.w;
      }
    }
#pragma unroll
    for (int i = 0; i < C_PER; ++i) {
      float d0 = 0.f, d1 = 0.f;
#pragma unroll
      for (int j = 0; j < 6; ++j) {
        const unsigned int p0 = wreg[RU_PER + i][2 * j], p1 = wreg[RU_PER + i][2 * j + 1];
        const float w0 = bflo(p0), w1 = bfhi(p0), w2 = bflo(p1), w3 = bfhi(p1);
        d0 = fmaf(w0, xv[0][j].x, fmaf(w1, xv[0][j].y, fmaf(w2, xv[0][j].z, fmaf(w3, xv[0][j].w, d0))));
        d1 = fmaf(w0, xv[1][j].x, fmaf(w1, xv[1][j].y, fmaf(w2, xv[1][j].z, fmaf(w3, xv[1][j].w, d1))));
      }
      d0 = wred_sum(d0);
      d1 = wred_sum(d1);
      if (lane < 2) {
        const int b = b0 + lane;
        const float dd = lane ? d1 : d0;
        const int row = c0g + i;
        const float c = tanhf(P_c[(size_t)(t * Bdim + b) * 768 + row] + dd);
        const float hp = h_all[(size_t)(t * Bdim + b) * DIM + row];  // L2-warm
        const float u = u_t[(size_t)(t * Bdim + b) * DIM + row];     // fresh line
        astore(&h_all[(size_t)((t + 1) * Bdim + b) * DIM + row], hp + u * (c - hp));
      }
    }
    gbar(leaf, go, root, g0, bidx++, xcd);
  }
}

// ---- deferred: out_all & copyq for all 1024 rows ----
__global__ void __launch_bounds__(256, 2) k_out(
    const float* __restrict__ Wo, const float* __restrict__ bo,
    const float* __restrict__ Wcp, const float* __restrict__ bcp,
    const float* __restrict__ h_all, float* __restrict__ out_all,
    float* __restrict__ copyq) {
  const int nb = blockIdx.x, tbc = blockIdx.y;
  const int n = nb * 256 + threadIdx.x;  // 0..1535
  const float* wrow;
  float bias;
  if (n < 768) { wrow = Wo + (size_t)n * 768;          bias = bo[n]; }
  else         { wrow = Wcp + (size_t)(n - 768) * 768; bias = bcp[n - 768]; }
  const float* hbase = h_all + (size_t)(tbc * 16 + 16) * DIM;  // h_new = slot t+1
  float acc[16];
#pragma unroll
  for (int i = 0; i < 16; ++i) acc[i] = bias;
  for (int k = 0; k < DIM; k += 4) {
    float4 w = *(const float4*)(wrow + k);
#pragma unroll
    for (int i = 0; i < 16; ++i) {
      float4 x = *(const float4*)(hbase + i * DIM + k);
      acc[i] = fmaf(w.x, x.x, fmaf(w.y, x.y, fmaf(w.z, x.z, fmaf(w.w, x.w, acc[i]))));
    }
  }
#pragma unroll
  for (int i = 0; i < 16; ++i) {
    int row = tbc * 16 + i;
    if (n < 768) out_all[(size_t)row * 768 + n] = acc[i];
    else         copyq[(size_t)row * 768 + (n - 768)] = acc[i];
  }
}

// ---- deferred: copy softmax num/den per (t,b) ----
__global__ void __launch_bounds__(512, 2) k_copy(
    const int* __restrict__ ids, const int* __restrict__ dtg,
    const float* __restrict__ ctx, const float* __restrict__ mask,
    const float* __restrict__ copyq,
    float* __restrict__ cnum, float* __restrict__ cden) {
  const int sc = blockIdx.x, b = blockIdx.y;
  const int lane = threadIdx.x & 63;
  const int seg = __builtin_amdgcn_readfirstlane(threadIdx.x >> 6);
  const int s = sc * 64 + lane;
  __shared__ float part[8][64];
  float creg[96];
  const float* crow = ctx + ((size_t)(b * ENC + s)) * DIM + seg * 96;
#pragma unroll
  for (int kk = 0; kk < 96; kk += 4) {
    float4 v = *(const float4*)(crow + kk);
    creg[kk] = v.x; creg[kk + 1] = v.y; creg[kk + 2] = v.z; creg[kk + 3] = v.w;
  }
  const float madd = (1.0f - mask[b * ENC + s]) * NEGF;
  const int myid = ids[b * ENC + s];
  for (int t = 0; t < Tn; ++t) {
    const int row = t * Bdim + b;
    const float* q = copyq + (size_t)row * 768 + seg * 96;
    float dot = 0.f;
#pragma unroll
    for (int kk = 0; kk < 96; kk += 4) {
      float4 qv = *(const float4*)(q + kk);
      dot = fmaf(qv.x, creg[kk], fmaf(qv.y, creg[kk + 1],
            fmaf(qv.z, creg[kk + 2], fmaf(qv.w, creg[kk + 3], dot))));
    }
    part[seg][lane] = dot;
    __syncthreads();
    if (threadIdx.x < 64) {
      float logit = madd;
#pragma unroll
      for (int w = 0; w < 8; ++w) logit += part[w][lane];
      float e = __expf(logit);
      int tgt = dtg[b * Tn + t];
      float ne = (myid == tgt) ? e : 0.f;
      float dsum = wred_sum(e);
      float nsum = wred_sum(ne);
      if (lane == 0) {
        atomicAdd(&cden[row], dsum);
        if (nsum != 0.f) atomicAdd(&cnum[row], nsum);
      }
    }
    __syncthreads();
  }
}

// ---- deferred: vocab exp-sum per row. grid (83, 32) x 256, 32 rows/block ----
__global__ void __launch_bounds__(256, 1) k_vocab(
    const float* __restrict__ emb, const float* __restrict__ out_all,
    float* __restrict__ S) {
  const int vc = blockIdx.x, tbc = blockIdx.y;
  const int tb0 = tbc * 32;
  const int v = vc * 256 + threadIdx.x;
  const bool valid = v < VOCAB;
  const int vv = valid ? v : 0;
  float acc[32];
#pragma unroll
  for (int i = 0; i < 32; ++i) acc[i] = 0.f;
  const float* erow = emb + (size_t)vv * DIM;
  for (int k = 0; k < DIM; k += 4) {
    float4 w = *(const float4*)(erow + k);
#pragma unroll
    for (int i = 0; i < 32; ++i) {
      float4 a = *(const float4*)(out_all + (size_t)(tb0 + i) * DIM + k);
      acc[i] = fmaf(w.x, a.x, fmaf(w.y, a.y, fmaf(w.z, a.z, fmaf(w.w, a.w, acc[i]))));
    }
  }
  __shared__ float rowsum[32];
  if (threadIdx.x < 32) rowsum[threadIdx.x] = 0.f;
  __syncthreads();
  const int lane = threadIdx.x & 63;
#pragma unroll
  for (int i = 0; i < 32; ++i) {
    float e = valid ? __expf(acc[i]) : 0.f;
    float r = wred_sum(e);
    if (lane == 0) atomicAdd(&rowsum[i], r);
  }
  __syncthreads();
  if (threadIdx.x < 32) atomicAdd(&S[tb0 + threadIdx.x], rowsum[threadIdx.x]);
}

// ---- deferred: per-row target prob + loss accumulation ----
__global__ void k_tgt(
    const int* __restrict__ dtg, const float* __restrict__ out_all,
    const float* __restrict__ emb, const float* __restrict__ Wm,
    const float* __restrict__ bm, const float* __restrict__ h_all,
    const float* __restrict__ S, const float* __restrict__ cnum,
    const float* __restrict__ cden, float* __restrict__ loss) {
  const int lane = threadIdx.x & 63;
  const int w = __builtin_amdgcn_readfirstlane(threadIdx.x >> 6);
  for (int rr = 0; rr < 16; ++rr) {
    const int row = (blockIdx.x * 4 + w) * 16 + rr;
    const int t = row >> 4, b = row & 15;
    const int tgt = dtg[b * Tn + t];
    const float* orow = out_all + (size_t)row * DIM + lane * 12;
    const float* erow = emb + (size_t)tgt * DIM + lane * 12;
    const float* hrow = h_all + (size_t)(row + 16) * DIM + lane * 12;
    const float* wm = Wm + lane * 12;
    float lt = 0.f, md = 0.f;
#pragma unroll
    for (int k = 0; k < 12; k += 4) {
      float4 o = *(const float4*)(orow + k);
      float4 e = *(const float4*)(erow + k);
      float4 h = *(const float4*)(hrow + k);
      float4 m = *(const float4*)(wm + k);
      lt = fmaf(o.x, e.x, fmaf(o.y, e.y, fmaf(o.z, e.z, fmaf(o.w, e.w, lt))));
      md = fmaf(m.x, h.x, fmaf(m.y, h.y, fmaf(m.z, h.z, fmaf(m.w, h.w, md))));
    }
    lt = wred_sum(lt);
    md = wred_sum(md);
    if (lane == 0 && tgt != 0) {
      float mode = sigmf(md + bm[0]);
      float pv = __expf(lt) / S[row] * mode;
      float den = cden[row];
      float pc = (den > 0.f) ? (cnum[row] / den) : 0.f;
      float p = pv + (1.0f - mode) * pc;
      atomicAdd(&loss[0], -logf(p + 1e-6f));
      atomicAdd(&loss[1], 1.0f);
    }
  }
}

__global__ void k_write(const float* __restrict__ loss, float* __restrict__ out) {
  if (threadIdx.x < Bdim) out[threadIdx.x] = loss[0] / loss[1];
}

extern "C" void kernel_launch(void* const* d_in, const int* in_sizes, int n_in,
                              void* d_out, int out_size, void* d_ws, size_t ws_size,
                              hipStream_t stream) {
  (void)in_sizes; (void)n_in; (void)out_size; (void)ws_size;
  const int*   input_ids = (const int*)d_in[0];
  const float* ctx       = (const float*)d_in[1];
  const float* cmask     = (const float*)d_in[2];
  const int*   din       = (const int*)d_in[3];
  const int*   dtg       = (const int*)d_in[4];
  const float* embW      = (const float*)d_in[7];
  const float* Wr = (const float*)d_in[8];  const float* br  = (const float*)d_in[9];
  const float* Wu = (const float*)d_in[10]; const float* bu  = (const float*)d_in[11];
  const float* Wc = (const float*)d_in[12]; const float* bc  = (const float*)d_in[13];
  const float* Wo = (const float*)d_in[14]; const float* bo  = (const float*)d_in[15];
  const float* Wcp= (const float*)d_in[16]; const float* bcp = (const float*)d_in[17];
  const float* Wm = (const float*)d_in[18]; const float* bm  = (const float*)d_in[19];
  const float* ih = (const float*)d_in[20];

  float* ws      = (float*)d_ws;
  float* P_ru    = ws;                          // 1024*1536
  float* P_c     = P_ru + 1024 * 1536;          // 1024*768
  float* h_all   = P_c + 1024 * 768;            // 65*16*768
  float* out_all = h_all + 65 * 16 * 768;       // 1024*768
  float* copyq   = out_all + 1024 * 768;        // 1024*768
  float* r_t     = copyq + 1024 * 768;          // 64*16*768 (per-t, fresh lines)
  float* u_t     = r_t + 64 * 16 * 768;         // 64*16*768
  // ---- coherently-zeroed region (IF-level only; no L2 copies anywhere) ----
  float* S       = u_t + 64 * 16 * 768;         // 1024
  float* cnum    = S + 1024;                    // 1024
  float* cden    = cnum + 1024;                 // 1024
  float* loss    = cden + 1024;                 // 2 (+30 pad -> 128B alignment)
  float* attnacc = loss + 32;                   // 64*16*768
  float* den     = attnacc + 64 * 16 * 768;     // 64*32 (128B per t slot)
  unsigned* root = (unsigned*)(den + 64 * 32);  // 1 ctr (128B line), IF-only
  const int nzero64 = (3 * 1024 + 32 + 64 * 16 * 768 + 64 * 32 + 32) / 2;
  // ---- XCD-L2-resident, NEVER zeroed (monotonic; mod/baseline logic) ----
  unsigned* slotctr = root + 32;                // 8 XCDs * 32 (128B stride)
  unsigned* leaf    = slotctr + 8 * 32;         // 8 * 32
  unsigned* go      = leaf + 8 * 32;            // 8 * 32

  hipFuncSetAttribute((const void*)k_seq,
                      hipFuncAttributeMaxDynamicSharedMemorySize, DYN_LDS);

  k_zero_coh<<<256, 1024, 0, stream>>>((unsigned long long*)S, nzero64);
  k_h0<<<12, 1024, 0, stream>>>(ih, h_all);
  k_pre<<<dim3(9, 64), 256, 0, stream>>>(din, embW, Wr, br, Wu, bu, Wc, bc, P_ru, P_c);

  k_seq<<<NBLK, 512, DYN_LDS, stream>>>(ctx, cmask, Wr, Wu, Wc, P_ru, P_c,
                                        h_all, attnacc, den, r_t, u_t,
                                        slotctr, leaf, go, root);

  k_out<<<dim3(6, 64), 256, 0, stream>>>(Wo, bo, Wcp, bcp, h_all, out_all, copyq);
  k_copy<<<dim3(8, 16), 512, 0, stream>>>(input_ids, dtg, ctx, cmask, copyq, cnum, cden);
  k_vocab<<<dim3(83, 32), 256, 0, stream>>>(embW, out_all, S);
  k_tgt<<<16, 256, 0, stream>>>(dtg, out_all, embW, Wm, bm, h_all, S, cnum, cden, loss);
  k_write<<<1, 64, 0, stream>>>(loss, (float*)d_out);
}

// Round 3
// 6120.780 us; speedup vs baseline: 1.2054x; 1.2054x over previous
//
#include <hip/hip_runtime.h>
#include <hip/hip_bf16.h>
#include <math.h>

// Problem constants (GRUAttnDecoder): B=16, ENC=512, T=64, DIM=768, VOCAB=21128
#define Bdim 16
#define ENC 512
#define Tn 64
#define DIM 768
#define VOCAB 21128
#define SCALEF 0.03608439182435161f  // 1/sqrt(768)
#define NEGF   -1e30f
#define NBLK 256
#define DYN_LDS (96 * 1024)  // forces 1 block/CU -> exactly 32 blocks per XCD

__device__ __forceinline__ float wred_sum(float v) {
#pragma unroll
  for (int m = 32; m >= 1; m >>= 1) v += __shfl_xor(v, m, 64);
  return v;
}
__device__ __forceinline__ float sigmf(float x) { return 1.0f / (1.0f + __expf(-x)); }

// coherent (IF-level) access helpers — the only cross-block primitives we use
__device__ __forceinline__ void astore(float* p, float v) {
  __hip_atomic_store(p, v, __ATOMIC_RELAXED, __HIP_MEMORY_SCOPE_AGENT);
}
__device__ __forceinline__ float aloadf(const float* p) {
  return __hip_atomic_load(const_cast<float*>(p), __ATOMIC_RELAXED, __HIP_MEMORY_SCOPE_AGENT);
}
__device__ __forceinline__ unsigned afadd(unsigned* p) {
  return __hip_atomic_fetch_add(p, 1u, __ATOMIC_RELAXED, __HIP_MEMORY_SCOPE_AGENT);
}
__device__ __forceinline__ unsigned aloadu(const unsigned* p) {
  return __hip_atomic_load(const_cast<unsigned*>(p), __ATOMIC_RELAXED, __HIP_MEMORY_SCOPE_AGENT);
}

// global barrier — baseline-proven form: leaf per (idx,xcd), every 32nd bumps
// root, all 256 block-leaders poll root (polling was shown NOT to be the cost).
__device__ __forceinline__ void gbar(unsigned* leaf, unsigned* root, int idx, int xcd) {
  __syncthreads();
  if (threadIdx.x == 0) {
    asm volatile("s_waitcnt vmcnt(0)" ::: "memory");
    unsigned prev = afadd(&leaf[(idx * 8 + xcd) * 16]);
    if (((prev + 1u) & 31u) == 0u) afadd(&root[idx * 16]);
    while (aloadu(&root[idx * 16]) < 8u) __builtin_amdgcn_s_sleep(1);
  }
  __syncthreads();
}
// XCD-local barrier: 32 blocks of one XCD, cumulative counter (zeroed/launch)
__device__ __forceinline__ void lbar(unsigned* lbc, int xcd, unsigned tgt) {
  __syncthreads();
  if (threadIdx.x == 0) {
    asm volatile("s_waitcnt vmcnt(0)" ::: "memory");
    afadd(&lbc[xcd * 16]);
    while (aloadu(&lbc[xcd * 16]) < tgt) __builtin_amdgcn_s_sleep(1);
  }
  __syncthreads();
}

// bf16 pack helpers (manual RNE)
__device__ __forceinline__ unsigned int f2bf(float f) {
  unsigned int u = __float_as_uint(f);
  u += 0x7fffu + ((u >> 16) & 1u);
  return u >> 16;
}
__device__ __forceinline__ float bflo(unsigned int p) { return __uint_as_float(p << 16); }
__device__ __forceinline__ float bfhi(unsigned int p) { return __uint_as_float(p & 0xffff0000u); }

// ---------------- init ----------------
__global__ void k_zero_coh(unsigned long long* __restrict__ p, int n64) {
  int i = blockIdx.x * blockDim.x + threadIdx.x;
  int st = gridDim.x * blockDim.x;
  for (; i < n64; i += st)
    __hip_atomic_store(&p[i], 0ULL, __ATOMIC_RELAXED, __HIP_MEMORY_SCOPE_AGENT);
}

__global__ void k_h0(const float* __restrict__ init_h, float* __restrict__ h_all) {
  int i = blockIdx.x * blockDim.x + threadIdx.x;
  if (i < Bdim * DIM) h_all[i] = init_h[i % DIM];
}

// ---- precompute emb-part of gate preactivations + bias for all (t,b) ----
__global__ void __launch_bounds__(256, 2) k_pre(
    const int* __restrict__ din, const float* __restrict__ emb,
    const float* __restrict__ Wr, const float* __restrict__ br,
    const float* __restrict__ Wu, const float* __restrict__ bu,
    const float* __restrict__ Wc, const float* __restrict__ bc,
    float* __restrict__ P_ru, float* __restrict__ P_c) {
  const int nb = blockIdx.x, tbc = blockIdx.y;
  const int n = nb * 256 + threadIdx.x;
  const float* wrow;
  float bias;
  if (n < 768)       { wrow = Wr + n * 2304 + 768;          bias = br[n]; }
  else if (n < 1536) { wrow = Wu + (n - 768) * 2304 + 768;  bias = bu[n - 768]; }
  else               { wrow = Wc + (n - 1536) * 2304 + 768; bias = bc[n - 1536]; }
  int id[16];
#pragma unroll
  for (int i = 0; i < 16; ++i) {
    int row = tbc * 16 + i;  // row = t*16 + b
    id[i] = din[(row & 15) * Tn + (row >> 4)];
  }
  float acc[16];
#pragma unroll
  for (int i = 0; i < 16; ++i) acc[i] = bias;
  for (int k = 0; k < DIM; k += 4) {
    float4 w = *(const float4*)(wrow + k);
#pragma unroll
    for (int i = 0; i < 16; ++i) {
      float4 x = *(const float4*)(emb + (size_t)id[i] * DIM + k);
      acc[i] = fmaf(w.x, x.x, fmaf(w.y, x.y, fmaf(w.z, x.z, fmaf(w.w, x.w, acc[i]))));
    }
  }
#pragma unroll
  for (int i = 0; i < 16; ++i) {
    int row = tbc * 16 + i;
    if (n < 1536) P_ru[(size_t)row * 1536 + n] = acc[i];
    else          P_c[(size_t)row * 768 + (n - 1536)] = acc[i];
  }
}

// ---- persistent sequential kernel — ZERO data atomics in the loop ----
// block identity: physical (xcd, slot<32). attention batch bA = 2*xcd+(slot&1),
// chunk = slot>>1 (32 enc positions). gid = xcd*32+slot owns r rows gid*3..,
// u rows = c rows = gid*3.. (u never leaves registers). wave w: batches 2w,2w+1.
// Per t: A1 (scores -> e_buf astore) | lbar | A2 (local den + normalized attn
// slice -> attnc astore) | gbar | B (r astore, u in regs) | gbar | C (c + h
// update astore) | gbar.
__global__ void __launch_bounds__(512, 1) k_seq(
    const float* __restrict__ ctx, const float* __restrict__ mask,
    const float* __restrict__ Wr, const float* __restrict__ Wu,
    const float* __restrict__ Wc,
    const float* __restrict__ P_ru, const float* __restrict__ P_c,
    float* __restrict__ h_all, float* __restrict__ attnc,
    float* __restrict__ r_coh, float* __restrict__ e_buf,
    unsigned* __restrict__ slotctr, unsigned* __restrict__ leaf,
    unsigned* __restrict__ root, unsigned* __restrict__ lbc) {
  extern __shared__ float dynpad[];   // 96KB requested; [512] used for e staging
  __shared__ int slot_sh;
  const int tid = threadIdx.x;
  const int lane = tid & 63;
  const int wv = tid >> 6;  // 0..7
  int xcd;
  asm volatile("s_getreg_b32 %0, hwreg(HW_REG_XCC_ID)" : "=s"(xcd));
  xcd &= 7;
  if (tid == 0) slot_sh = (int)afadd(&slotctr[xcd * 16]);
  __syncthreads();
  const int slot = slot_sh;            // 0..31 (1 block/CU guaranteed by LDS)
  const int gid = xcd * 32 + slot;     // 0..255 unique
  const int bA = 2 * xcd + (slot & 1); // attention batch
  const int chunk = slot >> 1;         // 0..15 (32 positions)
  const int dsl = chunk * 48;          // A2 dim-slice base
  const int rg0 = gid * 3;             // r rows 0..767
  const int cg0 = gid * 3;             // u & c rows 0..767
  const int b0 = 2 * wv;               // this wave's two batches

  // ---- stage 9 W rows (3 Wr, 3 Wu, 3 Wc) into per-lane VGPRs (bf16 packed)
  // lane cols (x-layout [a(768)|h(768)]): j<3 attn part, j>=3 h part
  unsigned int wreg[9][12];
#pragma unroll
  for (int i = 0; i < 9; ++i) {
    const float* src = (i < 3) ? (Wr + (size_t)(rg0 + i) * 2304)
                     : (i < 6) ? (Wu + (size_t)(cg0 + i - 3) * 2304)
                               : (Wc + (size_t)(cg0 + i - 6) * 2304);
#pragma unroll
    for (int j = 0; j < 6; ++j) {
      int xcol = 4 * lane + 256 * j;
      int scol = (j < 3) ? xcol : (1536 + xcol - 768);
      float4 v = *(const float4*)(src + scol);
      wreg[i][2 * j]     = (f2bf(v.x)) | (f2bf(v.y) << 16);
      wreg[i][2 * j + 1] = (f2bf(v.z)) | (f2bf(v.w) << 16);
    }
  }
  // attention mask-add for this wave's 4 positions
  float madd[4];
#pragma unroll
  for (int i = 0; i < 4; ++i)
    madd[i] = (1.0f - mask[bA * ENC + chunk * 32 + 4 * wv + i]) * NEGF;

  int bidx = 0;
  for (int t = 0; t < Tn; ++t) {
    // ============ A1: scores for this chunk (4 per wave), e -> e_buf ========
    {
      const float* hrow = h_all + (size_t)(t * Bdim + bA) * DIM;
      float hreg[12];
#pragma unroll
      for (int j = 0; j < 12; ++j) hreg[j] = hrow[lane + 64 * j];
#pragma unroll
      for (int i = 0; i < 4; ++i) {
        const int s = chunk * 32 + 4 * wv + i;
        const float* crow = ctx + ((size_t)(bA * ENC + s)) * DIM;
        float dot = 0.f;
#pragma unroll
        for (int j = 0; j < 12; ++j) dot = fmaf(crow[lane + 64 * j], hreg[j], dot);
        dot = wred_sum(dot);
        if (lane == 0)
          astore(&e_buf[bA * ENC + s], __expf(fmaf(dot, SCALEF, madd[i])));
      }
    }
    lbar(lbc, xcd, 32u * (unsigned)(t + 1));  // e_buf complete for this XCD's 2 batches

    // ==== A2: local den + pre-normalized attention slice (bA, 48 dims) ======
    {
      dynpad[tid] = aloadf(&e_buf[bA * ENC + tid]);  // 512 agent loads/block
      __syncthreads();
      float ev[8];
#pragma unroll
      for (int k = 0; k < 8; ++k) ev[k] = dynpad[lane + 64 * k];
      float den = 0.f;
#pragma unroll
      for (int k = 0; k < 8; ++k) den += ev[k];
      den = wred_sum(den);
      const float invd = 1.0f / den;
      const float* cb = ctx + (size_t)bA * ENC * DIM;
      int roff[8];
#pragma unroll
      for (int k = 0; k < 8; ++k) roff[k] = (lane + 64 * k) * DIM;
#pragma unroll
      for (int q = 0; q < 6; ++q) {
        const int d = dsl + wv * 6 + q;
        float acc = 0.f;
#pragma unroll
        for (int k = 0; k < 8; ++k) acc = fmaf(ev[k], cb[roff[k] + d], acc);
        acc = wred_sum(acc);
        if (lane == 0)
          astore(&attnc[(size_t)(t * Bdim + bA) * DIM + d], acc * invd);
      }
    }
    gbar(leaf, root, bidx++, xcd);

    // ============ B: r rows (astore) + u rows (stay in registers) ===========
    float4 xv[2][6];
#pragma unroll
    for (int bb = 0; bb < 2; ++bb) {
      const int b = b0 + bb;
      const float* ab = attnc + (size_t)(t * Bdim + b) * DIM;  // pre-normalized
      const float* hb = h_all + (size_t)(t * Bdim + b) * DIM;
#pragma unroll
      for (int j = 0; j < 3; ++j)
        xv[bb][j] = *(const float4*)(ab + 4 * lane + 256 * j);
#pragma unroll
      for (int j = 0; j < 3; ++j)
        xv[bb][3 + j] = *(const float4*)(hb + 4 * lane + 256 * j);
    }
    float u_reg[3];
#pragma unroll
    for (int i = 0; i < 3; ++i) {  // r rows rg0..rg0+2
      float d0 = 0.f, d1 = 0.f;
#pragma unroll
      for (int j = 0; j < 6; ++j) {
        const unsigned int p0 = wreg[i][2 * j], p1 = wreg[i][2 * j + 1];
        const float w0 = bflo(p0), w1 = bfhi(p0), w2 = bflo(p1), w3 = bfhi(p1);
        d0 = fmaf(w0, xv[0][j].x, fmaf(w1, xv[0][j].y, fmaf(w2, xv[0][j].z, fmaf(w3, xv[0][j].w, d0))));
        d1 = fmaf(w0, xv[1][j].x, fmaf(w1, xv[1][j].y, fmaf(w2, xv[1][j].z, fmaf(w3, xv[1][j].w, d1))));
      }
      d0 = wred_sum(d0);
      d1 = wred_sum(d1);
      if (lane < 2) {
        const int b = b0 + lane;
        const int row = rg0 + i;
        const float s = sigmf(P_ru[(size_t)(t * Bdim + b) * 1536 + row] + (lane ? d1 : d0));
        astore(&r_coh[(size_t)(t * Bdim + b) * DIM + row], s);
      }
    }
#pragma unroll
    for (int i = 0; i < 3; ++i) {  // u rows cg0..cg0+2 (register-resident)
      float d0 = 0.f, d1 = 0.f;
#pragma unroll
      for (int j = 0; j < 6; ++j) {
        const unsigned int p0 = wreg[3 + i][2 * j], p1 = wreg[3 + i][2 * j + 1];
        const float w0 = bflo(p0), w1 = bfhi(p0), w2 = bflo(p1), w3 = bfhi(p1);
        d0 = fmaf(w0, xv[0][j].x, fmaf(w1, xv[0][j].y, fmaf(w2, xv[0][j].z, fmaf(w3, xv[0][j].w, d0))));
        d1 = fmaf(w0, xv[1][j].x, fmaf(w1, xv[1][j].y, fmaf(w2, xv[1][j].z, fmaf(w3, xv[1][j].w, d1))));
      }
      d0 = wred_sum(d0);
      d1 = wred_sum(d1);
      if (lane < 2) {
        const int b = b0 + lane;
        u_reg[i] = sigmf(P_ru[(size_t)(t * Bdim + b) * 1536 + 768 + cg0 + i] + (lane ? d1 : d0));
      }
    }
    gbar(leaf, root, bidx++, xcd);

    // ============ C: c gate + h update (u from registers) ===================
#pragma unroll
    for (int bb = 0; bb < 2; ++bb) {
      const int b = b0 + bb;
      const float* rb = r_coh + (size_t)(t * Bdim + b) * DIM;
#pragma unroll
      for (int j = 0; j < 3; ++j) {
        float4 rv = *(const float4*)(rb + 4 * lane + 256 * j);  // fresh t-line
        xv[bb][3 + j].x *= rv.x; xv[bb][3 + j].y *= rv.y;
        xv[bb][3 + j].z *= rv.z; xv[bb][3 + j].w *= rv.w;
      }
    }
#pragma unroll
    for (int i = 0; i < 3; ++i) {
      float d0 = 0.f, d1 = 0.f;
#pragma unroll
      for (int j = 0; j < 6; ++j) {
        const unsigned int p0 = wreg[6 + i][2 * j], p1 = wreg[6 + i][2 * j + 1];
        const float w0 = bflo(p0), w1 = bfhi(p0), w2 = bflo(p1), w3 = bfhi(p1);
        d0 = fmaf(w0, xv[0][j].x, fmaf(w1, xv[0][j].y, fmaf(w2, xv[0][j].z, fmaf(w3, xv[0][j].w, d0))));
        d1 = fmaf(w0, xv[1][j].x, fmaf(w1, xv[1][j].y, fmaf(w2, xv[1][j].z, fmaf(w3, xv[1][j].w, d1))));
      }
      d0 = wred_sum(d0);
      d1 = wred_sum(d1);
      if (lane < 2) {
        const int b = b0 + lane;
        const int row = cg0 + i;
        const float c = tanhf(P_c[(size_t)(t * Bdim + b) * DIM + row] + (lane ? d1 : d0));
        const float hp = h_all[(size_t)(t * Bdim + b) * DIM + row];  // L2-warm
        astore(&h_all[(size_t)((t + 1) * Bdim + b) * DIM + row], hp + u_reg[i] * (c - hp));
      }
    }
    gbar(leaf, root, bidx++, xcd);
  }
}

// ---- deferred: out_all & copyq for all 1024 rows ----
__global__ void __launch_bounds__(256, 2) k_out(
    const float* __restrict__ Wo, const float* __restrict__ bo,
    const float* __restrict__ Wcp, const float* __restrict__ bcp,
    const float* __restrict__ h_all, float* __restrict__ out_all,
    float* __restrict__ copyq) {
  const int nb = blockIdx.x, tbc = blockIdx.y;
  const int n = nb * 256 + threadIdx.x;  // 0..1535
  const float* wrow;
  float bias;
  if (n < 768) { wrow = Wo + (size_t)n * 768;          bias = bo[n]; }
  else         { wrow = Wcp + (size_t)(n - 768) * 768; bias = bcp[n - 768]; }
  const float* hbase = h_all + (size_t)(tbc * 16 + 16) * DIM;  // h_new = slot t+1
  float acc[16];
#pragma unroll
  for (int i = 0; i < 16; ++i) acc[i] = bias;
  for (int k = 0; k < DIM; k += 4) {
    float4 w = *(const float4*)(wrow + k);
#pragma unroll
    for (int i = 0; i < 16; ++i) {
      float4 x = *(const float4*)(hbase + i * DIM + k);
      acc[i] = fmaf(w.x, x.x, fmaf(w.y, x.y, fmaf(w.z, x.z, fmaf(w.w, x.w, acc[i]))));
    }
  }
#pragma unroll
  for (int i = 0; i < 16; ++i) {
    int row = tbc * 16 + i;
    if (n < 768) out_all[(size_t)row * 768 + n] = acc[i];
    else         copyq[(size_t)row * 768 + (n - 768)] = acc[i];
  }
}

// ---- deferred: copy softmax num/den per (t,b) ----
__global__ void __launch_bounds__(512, 2) k_copy(
    const int* __restrict__ ids, const int* __restrict__ dtg,
    const float* __restrict__ ctx, const float* __restrict__ mask,
    const float* __restrict__ copyq,
    float* __restrict__ cnum, float* __restrict__ cden) {
  const int sc = blockIdx.x, b = blockIdx.y;
  const int lane = threadIdx.x & 63;
  const int seg = __builtin_amdgcn_readfirstlane(threadIdx.x >> 6);
  const int s = sc * 64 + lane;
  __shared__ float part[8][64];
  float creg[96];
  const float* crow = ctx + ((size_t)(b * ENC + s)) * DIM + seg * 96;
#pragma unroll
  for (int kk = 0; kk < 96; kk += 4) {
    float4 v = *(const float4*)(crow + kk);
    creg[kk] = v.x; creg[kk + 1] = v.y; creg[kk + 2] = v.z; creg[kk + 3] = v.w;
  }
  const float madd = (1.0f - mask[b * ENC + s]) * NEGF;
  const int myid = ids[b * ENC + s];
  for (int t = 0; t < Tn; ++t) {
    const int row = t * Bdim + b;
    const float* q = copyq + (size_t)row * 768 + seg * 96;
    float dot = 0.f;
#pragma unroll
    for (int kk = 0; kk < 96; kk += 4) {
      float4 qv = *(const float4*)(q + kk);
      dot = fmaf(qv.x, creg[kk], fmaf(qv.y, creg[kk + 1],
            fmaf(qv.z, creg[kk + 2], fmaf(qv.w, creg[kk + 3], dot))));
    }
    part[seg][lane] = dot;
    __syncthreads();
    if (threadIdx.x < 64) {
      float logit = madd;
#pragma unroll
      for (int w = 0; w < 8; ++w) logit += part[w][lane];
      float e = __expf(logit);
      int tgt = dtg[b * Tn + t];
      float ne = (myid == tgt) ? e : 0.f;
      float dsum = wred_sum(e);
      float nsum = wred_sum(ne);
      if (lane == 0) {
        atomicAdd(&cden[row], dsum);
        if (nsum != 0.f) atomicAdd(&cnum[row], nsum);
      }
    }
    __syncthreads();
  }
}

// ---- deferred: vocab exp-sum per row. grid (83, 32) x 256, 32 rows/block ----
__global__ void __launch_bounds__(256, 1) k_vocab(
    const float* __restrict__ emb, const float* __restrict__ out_all,
    float* __restrict__ S) {
  const int vc = blockIdx.x, tbc = blockIdx.y;
  const int tb0 = tbc * 32;
  const int v = vc * 256 + threadIdx.x;
  const bool valid = v < VOCAB;
  const int vv = valid ? v : 0;
  float acc[32];
#pragma unroll
  for (int i = 0; i < 32; ++i) acc[i] = 0.f;
  const float* erow = emb + (size_t)vv * DIM;
  for (int k = 0; k < DIM; k += 4) {
    float4 w = *(const float4*)(erow + k);
#pragma unroll
    for (int i = 0; i < 32; ++i) {
      float4 a = *(const float4*)(out_all + (size_t)(tb0 + i) * DIM + k);
      acc[i] = fmaf(w.x, a.x, fmaf(w.y, a.y, fmaf(w.z, a.z, fmaf(w.w, a.w, acc[i]))));
    }
  }
  __shared__ float rowsum[32];
  if (threadIdx.x < 32) rowsum[threadIdx.x] = 0.f;
  __syncthreads();
  const int lane = threadIdx.x & 63;
#pragma unroll
  for (int i = 0; i < 32; ++i) {
    float e = valid ? __expf(acc[i]) : 0.f;
    float r = wred_sum(e);
    if (lane == 0) atomicAdd(&rowsum[i], r);
  }
  __syncthreads();
  if (threadIdx.x < 32) atomicAdd(&S[tb0 + threadIdx.x], rowsum[threadIdx.x]);
}

// ---- deferred: per-row target prob + loss accumulation ----
__global__ void k_tgt(
    const int* __restrict__ dtg, const float* __restrict__ out_all,
    const float* __restrict__ emb, const float* __restrict__ Wm,
    const float* __restrict__ bm, const float* __restrict__ h_all,
    const float* __restrict__ S, const float* __restrict__ cnum,
    const float* __restrict__ cden, float* __restrict__ loss) {
  const int lane = threadIdx.x & 63;
  const int w = __builtin_amdgcn_readfirstlane(threadIdx.x >> 6);
  for (int rr = 0; rr < 16; ++rr) {
    const int row = (blockIdx.x * 4 + w) * 16 + rr;
    const int t = row >> 4, b = row & 15;
    const int tgt = dtg[b * Tn + t];
    const float* orow = out_all + (size_t)row * DIM + lane * 12;
    const float* erow = emb + (size_t)tgt * DIM + lane * 12;
    const float* hrow = h_all + (size_t)(row + 16) * DIM + lane * 12;
    const float* wm = Wm + lane * 12;
    float lt = 0.f, md = 0.f;
#pragma unroll
    for (int k = 0; k < 12; k += 4) {
      float4 o = *(const float4*)(orow + k);
      float4 e = *(const float4*)(erow + k);
      float4 h = *(const float4*)(hrow + k);
      float4 m = *(const float4*)(wm + k);
      lt = fmaf(o.x, e.x, fmaf(o.y, e.y, fmaf(o.z, e.z, fmaf(o.w, e.w, lt))));
      md = fmaf(m.x, h.x, fmaf(m.y, h.y, fmaf(m.z, h.z, fmaf(m.w, h.w, md))));
    }
    lt = wred_sum(lt);
    md = wred_sum(md);
    if (lane == 0 && tgt != 0) {
      float mode = sigmf(md + bm[0]);
      float pv = __expf(lt) / S[row] * mode;
      float den = cden[row];
      float pc = (den > 0.f) ? (cnum[row] / den) : 0.f;
      float p = pv + (1.0f - mode) * pc;
      atomicAdd(&loss[0], -logf(p + 1e-6f));
      atomicAdd(&loss[1], 1.0f);
    }
  }
}

__global__ void k_write(const float* __restrict__ loss, float* __restrict__ out) {
  if (threadIdx.x < Bdim) out[threadIdx.x] = loss[0] / loss[1];
}

extern "C" void kernel_launch(void* const* d_in, const int* in_sizes, int n_in,
                              void* d_out, int out_size, void* d_ws, size_t ws_size,
                              hipStream_t stream) {
  (void)in_sizes; (void)n_in; (void)out_size; (void)ws_size;
  const int*   input_ids = (const int*)d_in[0];
  const float* ctx       = (const float*)d_in[1];
  const float* cmask     = (const float*)d_in[2];
  const int*   din       = (const int*)d_in[3];
  const int*   dtg       = (const int*)d_in[4];
  const float* embW      = (const float*)d_in[7];
  const float* Wr = (const float*)d_in[8];  const float* br  = (const float*)d_in[9];
  const float* Wu = (const float*)d_in[10]; const float* bu  = (const float*)d_in[11];
  const float* Wc = (const float*)d_in[12]; const float* bc  = (const float*)d_in[13];
  const float* Wo = (const float*)d_in[14]; const float* bo  = (const float*)d_in[15];
  const float* Wcp= (const float*)d_in[16]; const float* bcp = (const float*)d_in[17];
  const float* Wm = (const float*)d_in[18]; const float* bm  = (const float*)d_in[19];
  const float* ih = (const float*)d_in[20];

  float* ws      = (float*)d_ws;
  float* P_ru    = ws;                          // 1024*1536
  float* P_c     = P_ru + 1024 * 1536;          // 1024*768
  float* h_all   = P_c + 1024 * 768;            // 65*16*768
  float* out_all = h_all + 65 * 16 * 768;       // 1024*768
  float* copyq   = out_all + 1024 * 768;        // 1024*768
  float* attnc   = copyq + 1024 * 768;          // 64*16*768 (pre-normalized attn)
  float* r_coh   = attnc + 64 * 16 * 768;       // 64*16*768 (per-t fresh lines)
  float* e_buf   = r_coh + 64 * 16 * 768;       // 16*512 (agent-only access)
  // ---- coherently-zeroed region ----
  float* S       = e_buf + 16 * 512;            // 1024
  float* cnum    = S + 1024;                    // 1024
  float* cden    = cnum + 1024;                 // 1024
  float* loss    = cden + 1024;                 // 2 (+30 pad -> 128B alignment)
  unsigned* slotctr = (unsigned*)(loss + 32);   // 8*16
  unsigned* leaf    = slotctr + 8 * 16;         // 192*8*16
  unsigned* root    = leaf + 192 * 8 * 16;      // 192*16
  unsigned* lbc     = root + 192 * 16;          // 8*16
  const int nzero64 = (3 * 1024 + 32 + 8 * 16 + 192 * 8 * 16 + 192 * 16 + 8 * 16) / 2;

  hipFuncSetAttribute((const void*)k_seq,
                      hipFuncAttributeMaxDynamicSharedMemorySize, DYN_LDS);

  k_zero_coh<<<64, 1024, 0, stream>>>((unsigned long long*)S, nzero64);
  k_h0<<<12, 1024, 0, stream>>>(ih, h_all);
  k_pre<<<dim3(9, 64), 256, 0, stream>>>(din, embW, Wr, br, Wu, bu, Wc, bc, P_ru, P_c);

  k_seq<<<NBLK, 512, DYN_LDS, stream>>>(ctx, cmask, Wr, Wu, Wc, P_ru, P_c,
                                        h_all, attnc, r_coh, e_buf,
                                        slotctr, leaf, root, lbc);

  k_out<<<dim3(6, 64), 256, 0, stream>>>(Wo, bo, Wcp, bcp, h_all, out_all, copyq);
  k_copy<<<dim3(8, 16), 512, 0, stream>>>(input_ids, dtg, ctx, cmask, copyq, cnum, cden);
  k_vocab<<<dim3(83, 32), 256, 0, stream>>>(embW, out_all, S);
  k_tgt<<<16, 256, 0, stream>>>(dtg, out_all, embW, Wm, bm, h_all, S, cnum, cden, loss);
  k_write<<<1, 64, 0, stream>>>(loss, (float*)d_out);
}

// Round 4
// 4285.603 us; speedup vs baseline: 1.7216x; 1.4282x over previous
//
#include <hip/hip_runtime.h>
#include <hip/hip_bf16.h>
#include <math.h>

// Problem constants (GRUAttnDecoder): B=16, ENC=512, T=64, DIM=768, VOCAB=21128
#define Bdim 16
#define ENC 512
#define Tn 64
#define DIM 768
#define VOCAB 21128
#define SCALEF 0.03608439182435161f  // 1/sqrt(768)
#define NEGF   -1e30f
#define NBLK 256
#define DYN_LDS (100 * 1024)  // 96KB ctx tile + scratch; forces 1 block/CU

__device__ __forceinline__ float wred_sum(float v) {
#pragma unroll
  for (int m = 32; m >= 1; m >>= 1) v += __shfl_xor(v, m, 64);
  return v;
}
__device__ __forceinline__ float sigmf(float x) { return 1.0f / (1.0f + __expf(-x)); }

// coherent (IF-level) access helpers — the only cross-block primitives we use
__device__ __forceinline__ void astore(float* p, float v) {
  __hip_atomic_store(p, v, __ATOMIC_RELAXED, __HIP_MEMORY_SCOPE_AGENT);
}
__device__ __forceinline__ void astore2(float* p, float a, float b) {
  float2 v = make_float2(a, b);
  __hip_atomic_store((unsigned long long*)p, *(unsigned long long*)&v,
                     __ATOMIC_RELAXED, __HIP_MEMORY_SCOPE_AGENT);
}
__device__ __forceinline__ float aloadf(const float* p) {
  return __hip_atomic_load(const_cast<float*>(p), __ATOMIC_RELAXED, __HIP_MEMORY_SCOPE_AGENT);
}
__device__ __forceinline__ unsigned afadd(unsigned* p) {
  return __hip_atomic_fetch_add(p, 1u, __ATOMIC_RELAXED, __HIP_MEMORY_SCOPE_AGENT);
}
__device__ __forceinline__ unsigned aloadu(const unsigned* p) {
  return __hip_atomic_load(const_cast<unsigned*>(p), __ATOMIC_RELAXED, __HIP_MEMORY_SCOPE_AGENT);
}

// global barrier — proven form: leaf per (idx,xcd), every 32nd bumps root,
// all block-leaders poll root.
__device__ __forceinline__ void gbar(unsigned* leaf, unsigned* root, int idx, int xcd) {
  __syncthreads();
  if (threadIdx.x == 0) {
    asm volatile("s_waitcnt vmcnt(0)" ::: "memory");
    unsigned prev = afadd(&leaf[(idx * 8 + xcd) * 16]);
    if (((prev + 1u) & 31u) == 0u) afadd(&root[idx * 16]);
    while (aloadu(&root[idx * 16]) < 8u) __builtin_amdgcn_s_sleep(1);
  }
  __syncthreads();
}
// XCD-local barrier: 32 blocks of one XCD, cumulative counter (zeroed/launch)
__device__ __forceinline__ void lbar(unsigned* lbc, int xcd, unsigned tgt) {
  __syncthreads();
  if (threadIdx.x == 0) {
    asm volatile("s_waitcnt vmcnt(0)" ::: "memory");
    afadd(&lbc[xcd * 16]);
    while (aloadu(&lbc[xcd * 16]) < tgt) __builtin_amdgcn_s_sleep(1);
  }
  __syncthreads();
}

// bf16 pack helpers (manual RNE)
__device__ __forceinline__ unsigned int f2bf(float f) {
  unsigned int u = __float_as_uint(f);
  u += 0x7fffu + ((u >> 16) & 1u);
  return u >> 16;
}
__device__ __forceinline__ float bflo(unsigned int p) { return __uint_as_float(p << 16); }
__device__ __forceinline__ float bfhi(unsigned int p) { return __uint_as_float(p & 0xffff0000u); }

// ---------------- init ----------------
__global__ void k_zero_coh(unsigned long long* __restrict__ p, int n64) {
  int i = blockIdx.x * blockDim.x + threadIdx.x;
  int st = gridDim.x * blockDim.x;
  for (; i < n64; i += st)
    __hip_atomic_store(&p[i], 0ULL, __ATOMIC_RELAXED, __HIP_MEMORY_SCOPE_AGENT);
}

__global__ void k_h0(const float* __restrict__ init_h, float* __restrict__ h_all) {
  int i = blockIdx.x * blockDim.x + threadIdx.x;
  if (i < Bdim * DIM) h_all[i] = init_h[i % DIM];
}

// ---- precompute emb-part of gate preactivations + bias for all (t,b) ----
__global__ void __launch_bounds__(256, 2) k_pre(
    const int* __restrict__ din, const float* __restrict__ emb,
    const float* __restrict__ Wr, const float* __restrict__ br,
    const float* __restrict__ Wu, const float* __restrict__ bu,
    const float* __restrict__ Wc, const float* __restrict__ bc,
    float* __restrict__ P_ru, float* __restrict__ P_c) {
  const int nb = blockIdx.x, tbc = blockIdx.y;
  const int n = nb * 256 + threadIdx.x;
  const float* wrow;
  float bias;
  if (n < 768)       { wrow = Wr + n * 2304 + 768;          bias = br[n]; }
  else if (n < 1536) { wrow = Wu + (n - 768) * 2304 + 768;  bias = bu[n - 768]; }
  else               { wrow = Wc + (n - 1536) * 2304 + 768; bias = bc[n - 1536]; }
  int id[16];
#pragma unroll
  for (int i = 0; i < 16; ++i) {
    int row = tbc * 16 + i;  // row = t*16 + b
    id[i] = din[(row & 15) * Tn + (row >> 4)];
  }
  float acc[16];
#pragma unroll
  for (int i = 0; i < 16; ++i) acc[i] = bias;
  for (int k = 0; k < DIM; k += 4) {
    float4 w = *(const float4*)(wrow + k);
#pragma unroll
    for (int i = 0; i < 16; ++i) {
      float4 x = *(const float4*)(emb + (size_t)id[i] * DIM + k);
      acc[i] = fmaf(w.x, x.x, fmaf(w.y, x.y, fmaf(w.z, x.z, fmaf(w.w, x.w, acc[i]))));
    }
  }
#pragma unroll
  for (int i = 0; i < 16; ++i) {
    int row = tbc * 16 + i;
    if (n < 1536) P_ru[(size_t)row * 1536 + n] = acc[i];
    else          P_c[(size_t)row * 768 + (n - 1536)] = acc[i];
  }
}

// ---- persistent sequential kernel — ctx lives in LDS for all 64 steps ----
// block identity: physical (xcd, slot<32). attention batch bA = 2*xcd+(slot&1),
// chunk = slot>>1 (32 enc positions, staged in LDS). gid = xcd*32+slot owns
// r rows gid*3.., u rows = c rows = gid*3.. (u never leaves registers).
// Per t: A1 (scores from LDS -> e_lds) | A2a (esum + 768-dim partial from LDS
// -> pbuf/psum astore) | lbar | A2b (sum 16 partials -> normalized attnc slice
// astore) | gbar | B (r astore, u regs) | gbar | C (c + h update astore) | gbar.
__global__ void __launch_bounds__(512, 1) k_seq(
    const float* __restrict__ ctx, const float* __restrict__ mask,
    const float* __restrict__ Wr, const float* __restrict__ Wu,
    const float* __restrict__ Wc,
    const float* __restrict__ P_ru, const float* __restrict__ P_c,
    float* __restrict__ h_all, float* __restrict__ attnc,
    float* __restrict__ r_coh, float* __restrict__ pbuf,
    float* __restrict__ psum,
    unsigned* __restrict__ slotctr, unsigned* __restrict__ leaf,
    unsigned* __restrict__ root, unsigned* __restrict__ lbc) {
  extern __shared__ float dynpad[];
  float* ctx_lds = dynpad;              // [32][768] = 24576 floats (96 KB)
  float* e_lds   = dynpad + 24576;      // [32]
  float* pred    = dynpad + 24576 + 32; // [48][17] padded = 816
  float* psh     = dynpad + 24576 + 32 + 816;  // [16]
  __shared__ int slot_sh;
  const int tid = threadIdx.x;
  const int lane = tid & 63;
  const int wv = tid >> 6;  // 0..7
  int xcd;
  asm volatile("s_getreg_b32 %0, hwreg(HW_REG_XCC_ID)" : "=s"(xcd));
  xcd &= 7;
  if (tid == 0) slot_sh = (int)afadd(&slotctr[xcd * 16]);
  __syncthreads();
  const int slot = slot_sh;            // 0..31 (1 block/CU guaranteed by LDS)
  const int gid = xcd * 32 + slot;     // 0..255 unique
  const int bA = 2 * xcd + (slot & 1); // attention batch
  const int chunk = slot >> 1;         // 0..15 (32 positions)
  const int dsl = chunk * 48;          // A2b dim-slice base
  const int rg0 = gid * 3;             // r rows 0..767
  const int cg0 = gid * 3;             // u & c rows 0..767
  const int b0 = 2 * wv;               // this wave's two batches (phases B/C)

  // ---- stage this block's ctx chunk (32 rows x 768) into LDS, ONCE ----
  {
    const float* chunkbase = ctx + ((size_t)(bA * ENC + chunk * 32)) * DIM;
#pragma unroll
    for (int k = 0; k < 12; ++k) {
      const int f = k * 2048 + tid * 4;
      *(float4*)(ctx_lds + f) = *(const float4*)(chunkbase + f);
    }
  }

  // ---- stage 9 W rows (3 Wr, 3 Wu, 3 Wc) into per-lane VGPRs (bf16 packed)
  unsigned int wreg[9][12];
#pragma unroll
  for (int i = 0; i < 9; ++i) {
    const float* src = (i < 3) ? (Wr + (size_t)(rg0 + i) * 2304)
                     : (i < 6) ? (Wu + (size_t)(cg0 + i - 3) * 2304)
                               : (Wc + (size_t)(cg0 + i - 6) * 2304);
#pragma unroll
    for (int j = 0; j < 6; ++j) {
      int xcol = 4 * lane + 256 * j;
      int scol = (j < 3) ? xcol : (1536 + xcol - 768);
      float4 v = *(const float4*)(src + scol);
      wreg[i][2 * j]     = (f2bf(v.x)) | (f2bf(v.y) << 16);
      wreg[i][2 * j + 1] = (f2bf(v.z)) | (f2bf(v.w) << 16);
    }
  }
  // attention mask-add for this wave's 4 positions
  float madd[4];
#pragma unroll
  for (int i = 0; i < 4; ++i)
    madd[i] = (1.0f - mask[bA * ENC + chunk * 32 + 4 * wv + i]) * NEGF;

  __syncthreads();  // ctx_lds ready for all waves

  int bidx = 0;
  for (int t = 0; t < Tn; ++t) {
    // ===== A1: scores for this chunk's 32 rows (4 per wave), from LDS ======
    {
      const float* hrow = h_all + (size_t)(t * Bdim + bA) * DIM;
      float hreg[12];
#pragma unroll
      for (int j = 0; j < 12; ++j) hreg[j] = hrow[lane + 64 * j];
#pragma unroll
      for (int i = 0; i < 4; ++i) {
        const int rr = 4 * wv + i;
        const float* crow = ctx_lds + rr * 768;
        float dot = 0.f;
#pragma unroll
        for (int j = 0; j < 12; ++j) dot = fmaf(crow[lane + 64 * j], hreg[j], dot);
        dot = wred_sum(dot);
        if (lane == 0) e_lds[rr] = __expf(fmaf(dot, SCALEF, madd[i]));
      }
    }
    __syncthreads();  // e_lds ready

    // ===== A2a: own esum + 768-dim weighted partial over own 32 LDS rows ===
    if (wv == 0) {
      float ev = (lane < 32) ? e_lds[lane] : 0.f;
      float es = wred_sum(ev);
      if (lane == 0) astore(&psum[bA * 16 + chunk], es);
    }
    if (tid < 384) {
      const int d0 = 2 * tid;
      float a0 = 0.f, a1 = 0.f;
#pragma unroll 8
      for (int r = 0; r < 32; ++r) {
        const float e = e_lds[r];
        const float2 c2 = *(const float2*)(ctx_lds + r * 768 + d0);
        a0 = fmaf(e, c2.x, a0);
        a1 = fmaf(e, c2.y, a1);
      }
      astore2(&pbuf[(size_t)(bA * 16 + chunk) * 768 + d0], a0, a1);
    }
    lbar(lbc, xcd, 32u * (unsigned)(t + 1));  // partials for this XCD's 2 batches done

    // ===== A2b: sum 16 partials (48-dim slice) + den -> normalized attnc ===
    {
      // coalesced agent reads: round 1 = offsets 0..31 x 16 chunks
      const int p1 = tid >> 5, o1 = tid & 31;
      float v1 = aloadf(&pbuf[(size_t)(bA * 16 + p1) * 768 + dsl + o1]);
      float v2 = 0.f;
      int p2 = 0, o2 = 0;
      if (tid < 256) {  // round 2 = offsets 32..47 x 16 chunks
        p2 = tid >> 4; o2 = 32 + (tid & 15);
        v2 = aloadf(&pbuf[(size_t)(bA * 16 + p2) * 768 + dsl + o2]);
      }
      if (tid < 16) psh[tid] = aloadf(&psum[bA * 16 + tid]);
      pred[o1 * 17 + p1] = v1;
      if (tid < 256) pred[o2 * 17 + p2] = v2;
      __syncthreads();
      if (tid < 48) {
        float s = 0.f, den = 0.f;
#pragma unroll
        for (int p = 0; p < 16; ++p) { s += pred[tid * 17 + p]; den += psh[p]; }
        astore(&attnc[(size_t)(t * Bdim + bA) * DIM + dsl + tid], s / den);
      }
    }
    gbar(leaf, root, bidx++, xcd);

    // ============ B: r rows (astore) + u rows (stay in registers) ===========
    float4 xv[2][6];
#pragma unroll
    for (int bb = 0; bb < 2; ++bb) {
      const int b = b0 + bb;
      const float* ab = attnc + (size_t)(t * Bdim + b) * DIM;  // pre-normalized
      const float* hb = h_all + (size_t)(t * Bdim + b) * DIM;
#pragma unroll
      for (int j = 0; j < 3; ++j)
        xv[bb][j] = *(const float4*)(ab + 4 * lane + 256 * j);
#pragma unroll
      for (int j = 0; j < 3; ++j)
        xv[bb][3 + j] = *(const float4*)(hb + 4 * lane + 256 * j);
    }
    float u_reg[3];
#pragma unroll
    for (int i = 0; i < 3; ++i) {  // r rows rg0..rg0+2
      float d0 = 0.f, d1 = 0.f;
#pragma unroll
      for (int j = 0; j < 6; ++j) {
        const unsigned int p0 = wreg[i][2 * j], p1 = wreg[i][2 * j + 1];
        const float w0 = bflo(p0), w1 = bfhi(p0), w2 = bflo(p1), w3 = bfhi(p1);
        d0 = fmaf(w0, xv[0][j].x, fmaf(w1, xv[0][j].y, fmaf(w2, xv[0][j].z, fmaf(w3, xv[0][j].w, d0))));
        d1 = fmaf(w0, xv[1][j].x, fmaf(w1, xv[1][j].y, fmaf(w2, xv[1][j].z, fmaf(w3, xv[1][j].w, d1))));
      }
      d0 = wred_sum(d0);
      d1 = wred_sum(d1);
      if (lane < 2) {
        const int b = b0 + lane;
        const int row = rg0 + i;
        const float s = sigmf(P_ru[(size_t)(t * Bdim + b) * 1536 + row] + (lane ? d1 : d0));
        astore(&r_coh[(size_t)(t * Bdim + b) * DIM + row], s);
      }
    }
#pragma unroll
    for (int i = 0; i < 3; ++i) {  // u rows cg0..cg0+2 (register-resident)
      float d0 = 0.f, d1 = 0.f;
#pragma unroll
      for (int j = 0; j < 6; ++j) {
        const unsigned int p0 = wreg[3 + i][2 * j], p1 = wreg[3 + i][2 * j + 1];
        const float w0 = bflo(p0), w1 = bfhi(p0), w2 = bflo(p1), w3 = bfhi(p1);
        d0 = fmaf(w0, xv[0][j].x, fmaf(w1, xv[0][j].y, fmaf(w2, xv[0][j].z, fmaf(w3, xv[0][j].w, d0))));
        d1 = fmaf(w0, xv[1][j].x, fmaf(w1, xv[1][j].y, fmaf(w2, xv[1][j].z, fmaf(w3, xv[1][j].w, d1))));
      }
      d0 = wred_sum(d0);
      d1 = wred_sum(d1);
      if (lane < 2) {
        const int b = b0 + lane;
        u_reg[i] = sigmf(P_ru[(size_t)(t * Bdim + b) * 1536 + 768 + cg0 + i] + (lane ? d1 : d0));
      }
    }
    gbar(leaf, root, bidx++, xcd);

    // ============ C: c gate + h update (u from registers) ===================
#pragma unroll
    for (int bb = 0; bb < 2; ++bb) {
      const int b = b0 + bb;
      const float* rb = r_coh + (size_t)(t * Bdim + b) * DIM;
#pragma unroll
      for (int j = 0; j < 3; ++j) {
        float4 rv = *(const float4*)(rb + 4 * lane + 256 * j);  // fresh t-line
        xv[bb][3 + j].x *= rv.x; xv[bb][3 + j].y *= rv.y;
        xv[bb][3 + j].z *= rv.z; xv[bb][3 + j].w *= rv.w;
      }
    }
#pragma unroll
    for (int i = 0; i < 3; ++i) {
      float d0 = 0.f, d1 = 0.f;
#pragma unroll
      for (int j = 0; j < 6; ++j) {
        const unsigned int p0 = wreg[6 + i][2 * j], p1 = wreg[6 + i][2 * j + 1];
        const float w0 = bflo(p0), w1 = bfhi(p0), w2 = bflo(p1), w3 = bfhi(p1);
        d0 = fmaf(w0, xv[0][j].x, fmaf(w1, xv[0][j].y, fmaf(w2, xv[0][j].z, fmaf(w3, xv[0][j].w, d0))));
        d1 = fmaf(w0, xv[1][j].x, fmaf(w1, xv[1][j].y, fmaf(w2, xv[1][j].z, fmaf(w3, xv[1][j].w, d1))));
      }
      d0 = wred_sum(d0);
      d1 = wred_sum(d1);
      if (lane < 2) {
        const int b = b0 + lane;
        const int row = cg0 + i;
        const float c = tanhf(P_c[(size_t)(t * Bdim + b) * DIM + row] + (lane ? d1 : d0));
        const float hp = h_all[(size_t)(t * Bdim + b) * DIM + row];
        astore(&h_all[(size_t)((t + 1) * Bdim + b) * DIM + row], hp + u_reg[i] * (c - hp));
      }
    }
    gbar(leaf, root, bidx++, xcd);
  }
}

// ---- deferred: out_all & copyq for all 1024 rows ----
__global__ void __launch_bounds__(256, 2) k_out(
    const float* __restrict__ Wo, const float* __restrict__ bo,
    const float* __restrict__ Wcp, const float* __restrict__ bcp,
    const float* __restrict__ h_all, float* __restrict__ out_all,
    float* __restrict__ copyq) {
  const int nb = blockIdx.x, tbc = blockIdx.y;
  const int n = nb * 256 + threadIdx.x;  // 0..1535
  const float* wrow;
  float bias;
  if (n < 768) { wrow = Wo + (size_t)n * 768;          bias = bo[n]; }
  else         { wrow = Wcp + (size_t)(n - 768) * 768; bias = bcp[n - 768]; }
  const float* hbase = h_all + (size_t)(tbc * 16 + 16) * DIM;  // h_new = slot t+1
  float acc[16];
#pragma unroll
  for (int i = 0; i < 16; ++i) acc[i] = bias;
  for (int k = 0; k < DIM; k += 4) {
    float4 w = *(const float4*)(wrow + k);
#pragma unroll
    for (int i = 0; i < 16; ++i) {
      float4 x = *(const float4*)(hbase + i * DIM + k);
      acc[i] = fmaf(w.x, x.x, fmaf(w.y, x.y, fmaf(w.z, x.z, fmaf(w.w, x.w, acc[i]))));
    }
  }
#pragma unroll
  for (int i = 0; i < 16; ++i) {
    int row = tbc * 16 + i;
    if (n < 768) out_all[(size_t)row * 768 + n] = acc[i];
    else         copyq[(size_t)row * 768 + (n - 768)] = acc[i];
  }
}

// ---- deferred: copy softmax num/den per (t,b) ----
__global__ void __launch_bounds__(512, 2) k_copy(
    const int* __restrict__ ids, const int* __restrict__ dtg,
    const float* __restrict__ ctx, const float* __restrict__ mask,
    const float* __restrict__ copyq,
    float* __restrict__ cnum, float* __restrict__ cden) {
  const int sc = blockIdx.x, b = blockIdx.y;
  const int lane = threadIdx.x & 63;
  const int seg = __builtin_amdgcn_readfirstlane(threadIdx.x >> 6);
  const int s = sc * 64 + lane;
  __shared__ float part[8][64];
  float creg[96];
  const float* crow = ctx + ((size_t)(b * ENC + s)) * DIM + seg * 96;
#pragma unroll
  for (int kk = 0; kk < 96; kk += 4) {
    float4 v = *(const float4*)(crow + kk);
    creg[kk] = v.x; creg[kk + 1] = v.y; creg[kk + 2] = v.z; creg[kk + 3] = v.w;
  }
  const float madd = (1.0f - mask[b * ENC + s]) * NEGF;
  const int myid = ids[b * ENC + s];
  for (int t = 0; t < Tn; ++t) {
    const int row = t * Bdim + b;
    const float* q = copyq + (size_t)row * 768 + seg * 96;
    float dot = 0.f;
#pragma unroll
    for (int kk = 0; kk < 96; kk += 4) {
      float4 qv = *(const float4*)(q + kk);
      dot = fmaf(qv.x, creg[kk], fmaf(qv.y, creg[kk + 1],
            fmaf(qv.z, creg[kk + 2], fmaf(qv.w, creg[kk + 3], dot))));
    }
    part[seg][lane] = dot;
    __syncthreads();
    if (threadIdx.x < 64) {
      float logit = madd;
#pragma unroll
      for (int w = 0; w < 8; ++w) logit += part[w][lane];
      float e = __expf(logit);
      int tgt = dtg[b * Tn + t];
      float ne = (myid == tgt) ? e : 0.f;
      float dsum = wred_sum(e);
      float nsum = wred_sum(ne);
      if (lane == 0) {
        atomicAdd(&cden[row], dsum);
        if (nsum != 0.f) atomicAdd(&cnum[row], nsum);
      }
    }
    __syncthreads();
  }
}

// ---- deferred: vocab exp-sum per row. grid (83, 32) x 256, 32 rows/block ----
__global__ void __launch_bounds__(256, 1) k_vocab(
    const float* __restrict__ emb, const float* __restrict__ out_all,
    float* __restrict__ S) {
  const int vc = blockIdx.x, tbc = blockIdx.y;
  const int tb0 = tbc * 32;
  const int v = vc * 256 + threadIdx.x;
  const bool valid = v < VOCAB;
  const int vv = valid ? v : 0;
  float acc[32];
#pragma unroll
  for (int i = 0; i < 32; ++i) acc[i] = 0.f;
  const float* erow = emb + (size_t)vv * DIM;
  for (int k = 0; k < DIM; k += 4) {
    float4 w = *(const float4*)(erow + k);
#pragma unroll
    for (int i = 0; i < 32; ++i) {
      float4 a = *(const float4*)(out_all + (size_t)(tb0 + i) * DIM + k);
      acc[i] = fmaf(w.x, a.x, fmaf(w.y, a.y, fmaf(w.z, a.z, fmaf(w.w, a.w, acc[i]))));
    }
  }
  __shared__ float rowsum[32];
  if (threadIdx.x < 32) rowsum[threadIdx.x] = 0.f;
  __syncthreads();
  const int lane = threadIdx.x & 63;
#pragma unroll
  for (int i = 0; i < 32; ++i) {
    float e = valid ? __expf(acc[i]) : 0.f;
    float r = wred_sum(e);
    if (lane == 0) atomicAdd(&rowsum[i], r);
  }
  __syncthreads();
  if (threadIdx.x < 32) atomicAdd(&S[tb0 + threadIdx.x], rowsum[threadIdx.x]);
}

// ---- deferred: per-row target prob + loss accumulation ----
__global__ void k_tgt(
    const int* __restrict__ dtg, const float* __restrict__ out_all,
    const float* __restrict__ emb, const float* __restrict__ Wm,
    const float* __restrict__ bm, const float* __restrict__ h_all,
    const float* __restrict__ S, const float* __restrict__ cnum,
    const float* __restrict__ cden, float* __restrict__ loss) {
  const int lane = threadIdx.x & 63;
  const int w = __builtin_amdgcn_readfirstlane(threadIdx.x >> 6);
  for (int rr = 0; rr < 16; ++rr) {
    const int row = (blockIdx.x * 4 + w) * 16 + rr;
    const int t = row >> 4, b = row & 15;
    const int tgt = dtg[b * Tn + t];
    const float* orow = out_all + (size_t)row * DIM + lane * 12;
    const float* erow = emb + (size_t)tgt * DIM + lane * 12;
    const float* hrow = h_all + (size_t)(row + 16) * DIM + lane * 12;
    const float* wm = Wm + lane * 12;
    float lt = 0.f, md = 0.f;
#pragma unroll
    for (int k = 0; k < 12; k += 4) {
      float4 o = *(const float4*)(orow + k);
      float4 e = *(const float4*)(erow + k);
      float4 h = *(const float4*)(hrow + k);
      float4 m = *(const float4*)(wm + k);
      lt = fmaf(o.x, e.x, fmaf(o.y, e.y, fmaf(o.z, e.z, fmaf(o.w, e.w, lt))));
      md = fmaf(m.x, h.x, fmaf(m.y, h.y, fmaf(m.z, h.z, fmaf(m.w, h.w, md))));
    }
    lt = wred_sum(lt);
    md = wred_sum(md);
    if (lane == 0 && tgt != 0) {
      float mode = sigmf(md + bm[0]);
      float pv = __expf(lt) / S[row] * mode;
      float den = cden[row];
      float pc = (den > 0.f) ? (cnum[row] / den) : 0.f;
      float p = pv + (1.0f - mode) * pc;
      atomicAdd(&loss[0], -logf(p + 1e-6f));
      atomicAdd(&loss[1], 1.0f);
    }
  }
}

__global__ void k_write(const float* __restrict__ loss, float* __restrict__ out) {
  if (threadIdx.x < Bdim) out[threadIdx.x] = loss[0] / loss[1];
}

extern "C" void kernel_launch(void* const* d_in, const int* in_sizes, int n_in,
                              void* d_out, int out_size, void* d_ws, size_t ws_size,
                              hipStream_t stream) {
  (void)in_sizes; (void)n_in; (void)out_size; (void)ws_size;
  const int*   input_ids = (const int*)d_in[0];
  const float* ctx       = (const float*)d_in[1];
  const float* cmask     = (const float*)d_in[2];
  const int*   din       = (const int*)d_in[3];
  const int*   dtg       = (const int*)d_in[4];
  const float* embW      = (const float*)d_in[7];
  const float* Wr = (const float*)d_in[8];  const float* br  = (const float*)d_in[9];
  const float* Wu = (const float*)d_in[10]; const float* bu  = (const float*)d_in[11];
  const float* Wc = (const float*)d_in[12]; const float* bc  = (const float*)d_in[13];
  const float* Wo = (const float*)d_in[14]; const float* bo  = (const float*)d_in[15];
  const float* Wcp= (const float*)d_in[16]; const float* bcp = (const float*)d_in[17];
  const float* Wm = (const float*)d_in[18]; const float* bm  = (const float*)d_in[19];
  const float* ih = (const float*)d_in[20];

  float* ws      = (float*)d_ws;
  float* P_ru    = ws;                          // 1024*1536
  float* P_c     = P_ru + 1024 * 1536;          // 1024*768
  float* h_all   = P_c + 1024 * 768;            // 65*16*768
  float* out_all = h_all + 65 * 16 * 768;       // 1024*768
  float* copyq   = out_all + 1024 * 768;        // 1024*768
  float* attnc   = copyq + 1024 * 768;          // 64*16*768 (normalized attn)
  float* r_coh   = attnc + 64 * 16 * 768;       // 64*16*768 (per-t fresh lines)
  float* pbuf    = r_coh + 64 * 16 * 768;       // 16*16*768 (agent-only access)
  float* psum    = pbuf + 16 * 16 * 768;        // 256      (agent-only access)
  // ---- coherently-zeroed region ----
  float* S       = psum + 256;                  // 1024
  float* cnum    = S + 1024;                    // 1024
  float* cden    = cnum + 1024;                 // 1024
  float* loss    = cden + 1024;                 // 2 (+30 pad -> 128B alignment)
  unsigned* slotctr = (unsigned*)(loss + 32);   // 8*16
  unsigned* leaf    = slotctr + 8 * 16;         // 192*8*16
  unsigned* root    = leaf + 192 * 8 * 16;      // 192*16
  unsigned* lbc     = root + 192 * 16;          // 8*16
  const int nzero64 = (3 * 1024 + 32 + 8 * 16 + 192 * 8 * 16 + 192 * 16 + 8 * 16) / 2;

  hipFuncSetAttribute((const void*)k_seq,
                      hipFuncAttributeMaxDynamicSharedMemorySize, DYN_LDS);

  k_zero_coh<<<64, 1024, 0, stream>>>((unsigned long long*)S, nzero64);
  k_h0<<<12, 1024, 0, stream>>>(ih, h_all);
  k_pre<<<dim3(9, 64), 256, 0, stream>>>(din, embW, Wr, br, Wu, bu, Wc, bc, P_ru, P_c);

  k_seq<<<NBLK, 512, DYN_LDS, stream>>>(ctx, cmask, Wr, Wu, Wc, P_ru, P_c,
                                        h_all, attnc, r_coh, pbuf, psum,
                                        slotctr, leaf, root, lbc);

  k_out<<<dim3(6, 64), 256, 0, stream>>>(Wo, bo, Wcp, bcp, h_all, out_all, copyq);
  k_copy<<<dim3(8, 16), 512, 0, stream>>>(input_ids, dtg, ctx, cmask, copyq, cnum, cden);
  k_vocab<<<dim3(83, 32), 256, 0, stream>>>(embW, out_all, S);
  k_tgt<<<16, 256, 0, stream>>>(dtg, out_all, embW, Wm, bm, h_all, S, cnum, cden, loss);
  k_write<<<1, 64, 0, stream>>>(loss, (float*)d_out);
}